// Round 9
// baseline (116.329 us; speedup 1.0000x reference)
//
#include <hip/hip_runtime.h>
#include <hip/hip_bf16.h>

// Problem constants
#define D_IN 1024
#define D_EMB 512
#define HIDDEN 256
#define NUM_CLASSES 64
#define N_SUPPORT 4096
#define N_QUERY 8192

typedef __bf16 bf16x8 __attribute__((ext_vector_type(8)));
typedef __bf16 bf16x4 __attribute__((ext_vector_type(4)));
typedef float f32x4 __attribute__((ext_vector_type(4)));

#define GLOAD_LDS16(g, l)                                                          \
  __builtin_amdgcn_global_load_lds(                                                \
      (const __attribute__((address_space(1))) unsigned int*)(g),                  \
      (__attribute__((address_space(3))) unsigned int*)(l), 16, 0, 0)

// ---------------------------------------------------------------------------
// prep: both weight transposes -> bf16 [cols][rows]
//   blocks [0,512):   W_e [1024][512] -> WeT [512][1024]
//   blocks [512,640): W1[:512][256]   -> WqT [256][512]
// ---------------------------------------------------------------------------
__global__ __launch_bounds__(256) void prep(
    const float* __restrict__ W_e, const float* __restrict__ W1,
    __bf16* __restrict__ WeT, __bf16* __restrict__ WqT) {
  __shared__ float tile[32][33];
  const int tid = threadIdx.x;
  int b = blockIdx.x;
  const float* in;
  __bf16* out;
  int bx, by, rows, cols;
  if (b < 512) {
    in = W_e; out = WeT; rows = D_IN; cols = D_EMB;
    bx = (b & 15) * 32; by = (b >> 4) * 32;
  } else {
    b -= 512;
    in = W1; out = WqT; rows = D_EMB; cols = HIDDEN;  // W1[:512] only
    bx = (b & 7) * 32; by = (b >> 3) * 32;
  }
  int tx = tid & 31, ty = tid >> 5;
#pragma unroll
  for (int i = ty; i < 32; i += 8)
    tile[i][tx] = in[(long)(by + i) * cols + bx + tx];
  __syncthreads();
#pragma unroll
  for (int i = ty; i < 32; i += 8)
    out[(long)(bx + i) * rows + by + tx] = (__bf16)tile[tx][i];
}

// ---------------------------------------------------------------------------
// Embedding GEMM, fp32-A-direct, depth-3 counted-vmcnt pipeline:
//   emb[12288][512] = relu( [support;query](fp32) @ WeT^T + b_e ) -> bf16
// BM=128, BN=64, BK=32, 4 waves (2x2), 4 LDS buffers (depth-3 prefetch).
// A staged as RAW fp32 via global_load_lds (async, counted vmcnt -- no reg
// round-trip), cvt to bf16 at fragment-read (VALU idle anyway). This deletes
// the 74 MB convert round-trip.
// Swizzles (rule #21, both-sides): A rows = 8x16B slots, slot ^= row&7;
// B rows = 4x16B slots, slot ^= (row>>1)&3. LDS dest linear, source
// column pre-swizzled, read slot swizzled.
// grid (96, 8): one m-tile's 8 n-tiles have linear ids differing by 96
// (96%8==0 -> same XCD) -> A re-reads are L2 hits.
// ---------------------------------------------------------------------------
__global__ __launch_bounds__(256, 3) void gemm_embf(
    const float* __restrict__ support, const float* __restrict__ query,
    const __bf16* __restrict__ BT, const float* __restrict__ bias,
    __bf16* __restrict__ C) {
  constexpr int BM = 128, BN = 64, BK = 32;
  constexpr int N = D_EMB, K = D_IN;
  constexpr int NT = K / BK;  // 32
  constexpr int MR = 4, NR = 2;
  constexpr int L = 5;  // gload_lds per thread per stage (4 A + 1 B)

  __shared__ __align__(16) float  Asf[4][BM * BK];  // 4 x 16 KB (fp32)
  __shared__ __align__(16) __bf16 Bs[4][BN * BK];   // 4 x 4 KB

  const int tid = threadIdx.x;
  const int wave = tid >> 6, lane = tid & 63;
  const int wr = wave >> 1, wc = wave & 1;
  const int l16 = lane & 15, half = lane >> 4;
  const int bslot = half ^ ((l16 >> 1) & 3);  // B read slot (bf16 rows)

  const int m0 = blockIdx.x * BM;
  const int n0 = blockIdx.y * BN;

  // block never straddles the support/query boundary (4096 % 128 == 0)
  const float* Abase = (m0 < N_SUPPORT)
                           ? support + (long)m0 * K
                           : query + (long)(m0 - N_SUPPORT) * K;

  // B staging: linear dest, inverse-swizzled source column
  const int brow = tid >> 2;
  const int bkc = (tid & 3) ^ ((brow >> 1) & 3);
  const __bf16* bptr = BT + (long)(n0 + brow) * K + bkc * 8;

  f32x4 acc[MR][NR];
#pragma unroll
  for (int m = 0; m < MR; ++m)
#pragma unroll
    for (int n = 0; n < NR; ++n) acc[m][n] = (f32x4)0.0f;

#define STAGE(t, buf)                                                       \
  {                                                                         \
    _Pragma("unroll") for (int q = 0; q < 4; ++q) {                         \
      int chunk = q * 256 + tid;   /* 16B chunk: 8 per row (fp32) */        \
      int row = chunk >> 3;                                                 \
      int kc = (chunk & 7) ^ (row & 7);                                     \
      GLOAD_LDS16(Abase + (long)row * K + (t) * BK + kc * 4,                \
                  &Asf[buf][chunk * 4]);                                    \
    }                                                                       \
    GLOAD_LDS16(bptr + (t) * BK, &Bs[buf][tid * 8]);                        \
  }

#define COMPUTE(buf)                                                        \
  {                                                                         \
    bf16x8 a[MR], b[NR];                                                    \
    _Pragma("unroll") for (int m = 0; m < MR; ++m) {                        \
      int row = wr * 64 + m * 16 + l16;                                     \
      int r7 = row & 7;                                                     \
      f32x4 lo = *(const f32x4*)(&Asf[buf][row * BK +                       \
                                           ((2 * half) ^ r7) * 4]);         \
      f32x4 hi = *(const f32x4*)(&Asf[buf][row * BK +                       \
                                           ((2 * half + 1) ^ r7) * 4]);     \
      bf16x8 t;                                                             \
      t[0] = (__bf16)lo[0]; t[1] = (__bf16)lo[1];                           \
      t[2] = (__bf16)lo[2]; t[3] = (__bf16)lo[3];                           \
      t[4] = (__bf16)hi[0]; t[5] = (__bf16)hi[1];                           \
      t[6] = (__bf16)hi[2]; t[7] = (__bf16)hi[3];                           \
      a[m] = t;                                                             \
    }                                                                       \
    _Pragma("unroll") for (int n = 0; n < NR; ++n)                          \
        b[n] = *(const bf16x8*)(&Bs[buf][(wc * 32 + n * 16 + l16) * BK +    \
                                         bslot * 8]);                       \
    _Pragma("unroll") for (int m = 0; m < MR; ++m)                          \
        _Pragma("unroll") for (int n = 0; n < NR; ++n)                      \
            acc[m][n] = __builtin_amdgcn_mfma_f32_16x16x32_bf16(            \
                a[m], b[n], acc[m][n], 0, 0, 0);                            \
  }

  // prologue: stage tiles 0,1,2
  STAGE(0, 0);
  STAGE(1, 1);
  STAGE(2, 2);
  asm volatile("s_waitcnt vmcnt(10)" ::: "memory");  // 2L: tile 0 landed
  __builtin_amdgcn_s_barrier();

  for (int t = 0; t < NT - 3; ++t) {
    STAGE(t + 3, (t + 3) & 3);
    COMPUTE(t & 3);
    asm volatile("s_waitcnt vmcnt(10)" ::: "memory");  // tile t+1 landed
    __builtin_amdgcn_s_barrier();
  }
  COMPUTE((NT - 3) & 3);
  asm volatile("s_waitcnt vmcnt(5)" ::: "memory");     // tile NT-2 landed
  __builtin_amdgcn_s_barrier();
  COMPUTE((NT - 2) & 3);
  asm volatile("s_waitcnt vmcnt(0)" ::: "memory");     // tile NT-1 landed
  __builtin_amdgcn_s_barrier();
  COMPUTE((NT - 1) & 3);

#undef STAGE
#undef COMPUTE

  // epilogue: C/D layout col = lane&15, row = (lane>>4)*4 + j  [m89/m91]
#pragma unroll
  for (int m = 0; m < MR; ++m)
#pragma unroll
    for (int n = 0; n < NR; ++n) {
      const int col = n0 + wc * 32 + n * 16 + l16;
      const float bv = bias[col];
#pragma unroll
      for (int j = 0; j < 4; ++j) {
        int row = m0 + wr * 64 + m * 16 + half * 4 + j;
        float v = fmaxf(acc[m][n][j] + bv, 0.0f);
        C[(long)row * N + col] = (__bf16)v;
      }
    }
}

// ---------------------------------------------------------------------------
// qp GEMM (bf16 A), depth-3 counted-vmcnt pipeline, 4 LDS buffers:
//   qp[8192][256] = q_emb @ WqT^T + b1   (f32 out)
// BM=64, BN=64, BK=32; grid (128, 4); L = 2 loads/thread/stage.
// ---------------------------------------------------------------------------
__global__ __launch_bounds__(256, 4) void gemm_qp(
    const __bf16* __restrict__ A, const __bf16* __restrict__ BT,
    const float* __restrict__ bias, float* __restrict__ C) {
  constexpr int BM = 64, BN = 64, BK = 32;
  constexpr int N = HIDDEN, K = D_EMB;
  constexpr int NT = K / BK;  // 16
  constexpr int MR = 2, NR = 2;

  __shared__ __align__(16) __bf16 As[4][BM * BK];  // 4 x 4 KB
  __shared__ __align__(16) __bf16 Bs[4][BN * BK];  // 4 x 4 KB

  const int tid = threadIdx.x;
  const int wave = tid >> 6, lane = tid & 63;
  const int wr = wave >> 1, wc = wave & 1;
  const int l16 = lane & 15, half = lane >> 4;
  const int slot = half ^ ((l16 >> 1) & 3);

  const int m0 = blockIdx.x * BM;
  const int n0 = blockIdx.y * BN;

  const int srow = tid >> 2;
  const int skc = (tid & 3) ^ ((srow >> 1) & 3);
  const __bf16* aptr = A + (long)(m0 + srow) * K + skc * 8;
  const __bf16* bptr = BT + (long)(n0 + srow) * K + skc * 8;

  f32x4 acc[MR][NR];
#pragma unroll
  for (int m = 0; m < MR; ++m)
#pragma unroll
    for (int n = 0; n < NR; ++n) acc[m][n] = (f32x4)0.0f;

#define STAGE(t, buf)                                                       \
  {                                                                         \
    GLOAD_LDS16(aptr + (t) * BK, &As[buf][tid * 8]);                        \
    GLOAD_LDS16(bptr + (t) * BK, &Bs[buf][tid * 8]);                        \
  }

#define COMPUTE(buf)                                                        \
  {                                                                         \
    bf16x8 a[MR], b[NR];                                                    \
    _Pragma("unroll") for (int m = 0; m < MR; ++m)                          \
        a[m] = *(const bf16x8*)(&As[buf][(wr * 32 + m * 16 + l16) * BK +    \
                                         slot * 8]);                        \
    _Pragma("unroll") for (int n = 0; n < NR; ++n)                          \
        b[n] = *(const bf16x8*)(&Bs[buf][(wc * 32 + n * 16 + l16) * BK +    \
                                         slot * 8]);                        \
    asm volatile("s_waitcnt lgkmcnt(0)" ::: "memory");                      \
    __builtin_amdgcn_sched_barrier(0);                                      \
    _Pragma("unroll") for (int m = 0; m < MR; ++m)                          \
        _Pragma("unroll") for (int n = 0; n < NR; ++n)                      \
            acc[m][n] = __builtin_amdgcn_mfma_f32_16x16x32_bf16(            \
                a[m], b[n], acc[m][n], 0, 0, 0);                            \
  }

  STAGE(0, 0);
  STAGE(1, 1);
  STAGE(2, 2);
  asm volatile("s_waitcnt vmcnt(4)" ::: "memory");  // tile 0 landed
  __builtin_amdgcn_s_barrier();

  for (int t = 0; t < NT - 3; ++t) {
    STAGE(t + 3, (t + 3) & 3);
    COMPUTE(t & 3);
    asm volatile("s_waitcnt vmcnt(4)" ::: "memory");  // tile t+1 landed
    __builtin_amdgcn_s_barrier();
  }
  COMPUTE((NT - 3) & 3);
  asm volatile("s_waitcnt vmcnt(2)" ::: "memory");
  __builtin_amdgcn_s_barrier();
  COMPUTE((NT - 2) & 3);
  asm volatile("s_waitcnt vmcnt(0)" ::: "memory");
  __builtin_amdgcn_s_barrier();
  COMPUTE((NT - 1) & 3);

#undef STAGE
#undef COMPUTE

#pragma unroll
  for (int m = 0; m < MR; ++m)
#pragma unroll
    for (int n = 0; n < NR; ++n) {
      const int col = n0 + wc * 32 + n * 16 + l16;
      const float bv = bias[col];
#pragma unroll
      for (int j = 0; j < 4; ++j) {
        int row = m0 + wr * 32 + m * 16 + half * 4 + j;
        C[(long)row * N + col] = acc[m][n][j] + bv;
      }
    }
}

// ---------------------------------------------------------------------------
// class partial sums, no atomics / no zero-init. grid (64 classes, 8 slices).
// ---------------------------------------------------------------------------
__global__ __launch_bounds__(256) void proto_partial(
    const __bf16* __restrict__ s_emb, const int* __restrict__ labels,
    float* __restrict__ sums_part, int* __restrict__ cnt_part) {
  const int c = blockIdx.x;
  const int s = blockIdx.y;  // 0..7
  const int tid = threadIdx.x;
  const int j0 = s * (N_SUPPORT / 8);
  float a0 = 0.0f, a1 = 0.0f;
  int count = 0;
#pragma unroll 4
  for (int j = j0; j < j0 + N_SUPPORT / 8; j += 4) {
    int4 lab4 = *(const int4*)(labels + j);
#pragma unroll
    for (int u = 0; u < 4; ++u) {
      int lab = (u == 0) ? lab4.x : (u == 1) ? lab4.y : (u == 2) ? lab4.z : lab4.w;
      if (lab == c) {
        const __bf16* r = s_emb + (long)(j + u) * D_EMB;
        a0 += (float)r[tid];
        a1 += (float)r[tid + 256];
        ++count;
      }
    }
  }
  float* dst = sums_part + (long)(c * 8 + s) * D_EMB;
  dst[tid] = a0;
  dst[tid + 256] = a1;
  if (tid == 0) cnt_part[c * 8 + s] = count;
}

// ---------------------------------------------------------------------------
// cpb_part[kc][c][n] = sum_{k in chunk kc} means[c][k] * W1[(D_EMB+k)][n]
// grid (64, 4). b1 folded into qp GEMM bias. Summed in score staging.
// ---------------------------------------------------------------------------
__global__ __launch_bounds__(256) void proto_cpb(
    const float* __restrict__ sums_part, const int* __restrict__ cnt_part,
    const float* __restrict__ W1, float* __restrict__ cpb_part) {
  __shared__ float ls[128];
  const int c = blockIdx.x;
  const int kc = blockIdx.y;
  const int k0 = kc * 128;
  const int tid = threadIdx.x;

  int nc = 0;
#pragma unroll
  for (int s = 0; s < 8; ++s) nc += cnt_part[c * 8 + s];
  float inv = 1.0f / fmaxf((float)nc, 1.0f);

  if (tid < 128) {
    float v = 0.0f;
#pragma unroll
    for (int s = 0; s < 8; ++s)
      v += sums_part[(long)(c * 8 + s) * D_EMB + k0 + tid];
    ls[tid] = v * inv;
  }
  __syncthreads();

  float acc = 0.0f;
#pragma unroll 8
  for (int k = 0; k < 128; ++k)
    acc = fmaf(ls[k], W1[(long)(D_EMB + k0 + k) * HIDDEN + tid], acc);
  cpb_part[((long)kc * NUM_CLASSES + c) * HIDDEN + tid] = acc;
}

// ---------------------------------------------------------------------------
// fused score: out[q][c] = sigmoid( sum_k relu(qp[q,k]+cpb[c,k]) * W2[k] + b2 )
// qp already includes b1. cpb_part summed during staging.
// lane = class c; wave handles 8 q-rows; block = 4 waves = 32 q-rows.
// ---------------------------------------------------------------------------
__global__ __launch_bounds__(256) void score_kernel(
    const float* __restrict__ qp, const float* __restrict__ cpb_part,
    const float* __restrict__ W2, const float* __restrict__ b2,
    float* __restrict__ out) {
  constexpr int CPB_S = 260;  // f32 stride: 1040 B, 16B aligned
  __shared__ __align__(16) float cpb_s[NUM_CLASSES * CPB_S];
  __shared__ __align__(16) float qp_s[32 * HIDDEN];
  __shared__ __align__(16) float w2_s[HIDDEN];

  const int tid = threadIdx.x;
  const int w = tid >> 6;
  const int c = tid & 63;
  const int qb0 = blockIdx.x * 32;
  constexpr int NCH = NUM_CLASSES * HIDDEN;

  w2_s[tid] = W2[tid];
  for (int i = tid; i < NCH; i += 256)
    cpb_s[(i >> 8) * CPB_S + (i & (HIDDEN - 1))] =
        cpb_part[i] + cpb_part[NCH + i] + cpb_part[2 * NCH + i] +
        cpb_part[3 * NCH + i];
  for (int i = tid; i < 32 * HIDDEN; i += 256)
    qp_s[i] = qp[(long)qb0 * HIDDEN + i];
  __syncthreads();

  const float bb = b2[0];
  float acc[8];
#pragma unroll
  for (int q = 0; q < 8; ++q) acc[q] = 0.0f;

  const float* crow = cpb_s + c * CPB_S;
  const float* qbase = qp_s + (w * 8) * HIDDEN;

#pragma unroll 4
  for (int kc = 0; kc < HIDDEN / 4; ++kc) {
    f32x4 cv = *(const f32x4*)(crow + kc * 4);
    f32x4 wv = *(const f32x4*)(w2_s + kc * 4);
#pragma unroll
    for (int q = 0; q < 8; ++q) {
      f32x4 qv = *(const f32x4*)(qbase + q * HIDDEN + kc * 4);
      acc[q] = fmaf(fmaxf(qv[0] + cv[0], 0.0f), wv[0], acc[q]);
      acc[q] = fmaf(fmaxf(qv[1] + cv[1], 0.0f), wv[1], acc[q]);
      acc[q] = fmaf(fmaxf(qv[2] + cv[2], 0.0f), wv[2], acc[q]);
      acc[q] = fmaf(fmaxf(qv[3] + cv[3], 0.0f), wv[3], acc[q]);
    }
  }

#pragma unroll
  for (int q = 0; q < 8; ++q) {
    float x = acc[q] + bb;
    out[(long)(qb0 + w * 8 + q) * NUM_CLASSES + c] = 1.0f / (1.0f + __expf(-x));
  }
}

// ---------------------------------------------------------------------------
extern "C" void kernel_launch(void* const* d_in, const int* in_sizes, int n_in,
                              void* d_out, int out_size, void* d_ws,
                              size_t ws_size, hipStream_t stream) {
  const float* support = (const float*)d_in[0];
  const float* query   = (const float*)d_in[1];
  const int*   labels  = (const int*)d_in[2];
  const float* W_e     = (const float*)d_in[3];
  const float* b_e     = (const float*)d_in[4];
  const float* W1      = (const float*)d_in[5];
  const float* b1      = (const float*)d_in[6];
  const float* W2      = (const float*)d_in[7];
  const float* b2      = (const float*)d_in[8];
  float* out = (float*)d_out;

  char* ws = (char*)d_ws;
  size_t off = 0;
  auto alloc = [&](size_t bytes) {
    void* p = ws + off;
    off = (off + bytes + 255) & ~(size_t)255;
    return p;
  };
  const long NTOT = N_SUPPORT + N_QUERY;  // 12288
  __bf16* WeT = (__bf16*)alloc((size_t)D_EMB * D_IN * 2);           // 1 MB
  __bf16* WqT = (__bf16*)alloc((size_t)HIDDEN * D_EMB * 2);         // 256 KB
  __bf16* emb = (__bf16*)alloc((size_t)NTOT * D_EMB * 2);           // 12.6 MB
  float*  qp  = (float*)alloc((size_t)N_QUERY * HIDDEN * 4);        // 8.4 MB
  float*  sums_part = (float*)alloc((size_t)NUM_CLASSES * 8 * D_EMB * 4);
  int*    cnt_part  = (int*)alloc((size_t)NUM_CLASSES * 8 * 4);
  float*  cpb_part  = (float*)alloc((size_t)4 * NUM_CLASSES * HIDDEN * 4);

  // weight transposes only (fp32 A consumed directly by gemm_embf)
  prep<<<640, 256, 0, stream>>>(W_e, W1, WeT, WqT);

  // embeddings: relu([support;query](fp32) @ W_e + b_e) -> bf16 [12288][512]
  gemm_embf<<<dim3(NTOT / 128, D_EMB / 64), 256, 0, stream>>>(
      support, query, WeT, b_e, emb);

  // class prototypes: partial sums (no atomics) -> projection parts
  proto_partial<<<dim3(NUM_CLASSES, 8), 256, 0, stream>>>(emb, labels, sums_part,
                                                          cnt_part);
  proto_cpb<<<dim3(NUM_CLASSES, 4), 256, 0, stream>>>(sums_part, cnt_part, W1,
                                                      cpb_part);

  // qp = q_emb @ Wq + b1  (f32 out [8192][256])
  gemm_qp<<<dim3(N_QUERY / 64, HIDDEN / 64), 256, 0, stream>>>(
      emb + (long)N_SUPPORT * D_EMB, WqT, b1, qp);

  // fused relation score (cpb_part summed in staging)
  score_kernel<<<N_QUERY / 32, 256, 0, stream>>>(qp, cpb_part, W2, b2, out);
}

// Round 10
// 87.545 us; speedup vs baseline: 1.3288x; 1.3288x over previous
//
#include <hip/hip_runtime.h>
#include <hip/hip_bf16.h>

// Problem constants
#define D_IN 1024
#define D_EMB 512
#define HIDDEN 256
#define NUM_CLASSES 64
#define N_SUPPORT 4096
#define N_QUERY 8192

typedef __bf16 bf16x8 __attribute__((ext_vector_type(8)));
typedef __bf16 bf16x4 __attribute__((ext_vector_type(4)));
typedef float f32x4 __attribute__((ext_vector_type(4)));

#define GLOAD_LDS16(g, l)                                                          \
  __builtin_amdgcn_global_load_lds(                                                \
      (const __attribute__((address_space(1))) unsigned int*)(g),                  \
      (__attribute__((address_space(3))) unsigned int*)(l), 16, 0, 0)

// ---------------------------------------------------------------------------
// prep: weight transposes + fp32->bf16 convert (one dispatch, as in R7)
//   blocks [0,512):    W_e [1024][512] -> WeT [512][1024]
//   blocks [512,640):  W1[:512][256]   -> WqT [256][512]
//   blocks [640,3712): [support;query] fp32 -> Xbf bf16, 4096 elems/block
// ---------------------------------------------------------------------------
__global__ __launch_bounds__(256) void prep(
    const float* __restrict__ W_e, const float* __restrict__ W1,
    const float* __restrict__ support, const float* __restrict__ query,
    __bf16* __restrict__ WeT, __bf16* __restrict__ WqT,
    __bf16* __restrict__ Xbf) {
  const int tid = threadIdx.x;
  int b = blockIdx.x;
  if (b < 640) {
    __shared__ float tile[32][33];
    const float* in;
    __bf16* out;
    int bx, by, rows, cols;
    if (b < 512) {
      in = W_e; out = WeT; rows = D_IN; cols = D_EMB;
      bx = (b & 15) * 32; by = (b >> 4) * 32;
    } else {
      b -= 512;
      in = W1; out = WqT; rows = D_EMB; cols = HIDDEN;  // W1[:512] only
      bx = (b & 7) * 32; by = (b >> 3) * 32;
    }
    int tx = tid & 31, ty = tid >> 5;
#pragma unroll
    for (int i = ty; i < 32; i += 8)
      tile[i][tx] = in[(long)(by + i) * cols + bx + tx];
    __syncthreads();
#pragma unroll
    for (int i = ty; i < 32; i += 8)
      out[(long)(bx + i) * rows + by + tx] = (__bf16)tile[tx][i];
  } else {
    const long nsup = (long)N_SUPPORT * D_IN;
    long base = (long)(b - 640) * 4096;
#pragma unroll
    for (int g = 0; g < 4; ++g) {
      long i = base + g * 1024 + tid * 4;
      const float* src = (i < nsup) ? (support + i) : (query + (i - nsup));
      float4 v = *(const float4*)src;
      bf16x4 o;
      o[0] = (__bf16)v.x; o[1] = (__bf16)v.y;
      o[2] = (__bf16)v.z; o[3] = (__bf16)v.w;
      *(bf16x4*)(Xbf + i) = o;
    }
  }
}

// ---------------------------------------------------------------------------
// Embedding GEMM, bf16 A, depth-3 counted-vmcnt pipeline, 4 LDS buffers:
//   emb[12288][512] = relu( Xbf @ WeT^T + b_e ) -> bf16
// BM=128, BN=64, BK=32, 4 waves (2x2). LDS 48 KB -> 3 blocks/CU.
// L = 3 gload_lds/wave/stage (2 A + 1 B); steady wait vmcnt(6) = 2 stages
// in flight; tail 3, 0. Swizzle identical to R7 (measured 0 conflicts).
// grid (96,8): same m-tile's n-tiles land on one XCD (96%8==0) -> A L2-hot.
// ---------------------------------------------------------------------------
__global__ __launch_bounds__(256, 3) void gemm_emb(
    const __bf16* __restrict__ A, const __bf16* __restrict__ BT,
    const float* __restrict__ bias, __bf16* __restrict__ C) {
  constexpr int BM = 128, BN = 64, BK = 32;
  constexpr int N = D_EMB, K = D_IN;
  constexpr int NT = K / BK;  // 32
  constexpr int MR = 4, NR = 2;

  __shared__ __align__(16) __bf16 As[4][BM * BK];  // 4 x 8 KB
  __shared__ __align__(16) __bf16 Bs[4][BN * BK];  // 4 x 4 KB

  const int tid = threadIdx.x;
  const int wave = tid >> 6, lane = tid & 63;
  const int wr = wave >> 1, wc = wave & 1;
  const int l16 = lane & 15, half = lane >> 4;
  const int slot = half ^ ((l16 >> 1) & 3);

  const int m0 = blockIdx.x * BM;
  const int n0 = blockIdx.y * BN;

  // staging addresses (linear LDS dest, inverse-swizzled source column)
  const int ar0 = tid >> 2;                       // chunk tid row
  const int ak0 = (tid & 3) ^ ((ar0 >> 1) & 3);
  const int ar1 = (tid + 256) >> 2;               // chunk tid+256 row
  const int ak1 = (tid & 3) ^ ((ar1 >> 1) & 3);
  const __bf16* aptr0 = A + (long)(m0 + ar0) * K + ak0 * 8;
  const __bf16* aptr1 = A + (long)(m0 + ar1) * K + ak1 * 8;
  const int brow = tid >> 2;
  const int bkc = (tid & 3) ^ ((brow >> 1) & 3);
  const __bf16* bptr = BT + (long)(n0 + brow) * K + bkc * 8;

  f32x4 acc[MR][NR];
#pragma unroll
  for (int m = 0; m < MR; ++m)
#pragma unroll
    for (int n = 0; n < NR; ++n) acc[m][n] = (f32x4)0.0f;

#define STAGE(t, buf)                                                       \
  {                                                                         \
    GLOAD_LDS16(aptr0 + (t) * BK, &As[buf][tid * 8]);                       \
    GLOAD_LDS16(aptr1 + (t) * BK, &As[buf][(tid + 256) * 8]);               \
    GLOAD_LDS16(bptr + (t) * BK, &Bs[buf][tid * 8]);                        \
  }

#define COMPUTE(buf)                                                        \
  {                                                                         \
    bf16x8 a[MR], b[NR];                                                    \
    _Pragma("unroll") for (int m = 0; m < MR; ++m)                          \
        a[m] = *(const bf16x8*)(&As[buf][(wr * 64 + m * 16 + l16) * BK +    \
                                         slot * 8]);                        \
    _Pragma("unroll") for (int n = 0; n < NR; ++n)                          \
        b[n] = *(const bf16x8*)(&Bs[buf][(wc * 32 + n * 16 + l16) * BK +    \
                                         slot * 8]);                        \
    asm volatile("s_waitcnt lgkmcnt(0)" ::: "memory");                      \
    __builtin_amdgcn_sched_barrier(0);                                      \
    _Pragma("unroll") for (int m = 0; m < MR; ++m)                          \
        _Pragma("unroll") for (int n = 0; n < NR; ++n)                      \
            acc[m][n] = __builtin_amdgcn_mfma_f32_16x16x32_bf16(            \
                a[m], b[n], acc[m][n], 0, 0, 0);                            \
  }

  // prologue: stage tiles 0,1,2 (9 loads in flight)
  STAGE(0, 0);
  STAGE(1, 1);
  STAGE(2, 2);
  asm volatile("s_waitcnt vmcnt(6)" ::: "memory");  // tile 0 landed
  __builtin_amdgcn_s_barrier();

  for (int t = 0; t < NT - 3; ++t) {
    STAGE(t + 3, (t + 3) & 3);
    COMPUTE(t & 3);
    asm volatile("s_waitcnt vmcnt(6)" ::: "memory");  // tile t+1 landed
    __builtin_amdgcn_s_barrier();
  }
  COMPUTE((NT - 3) & 3);
  asm volatile("s_waitcnt vmcnt(3)" ::: "memory");    // tile NT-2 landed
  __builtin_amdgcn_s_barrier();
  COMPUTE((NT - 2) & 3);
  asm volatile("s_waitcnt vmcnt(0)" ::: "memory");    // tile NT-1 landed
  __builtin_amdgcn_s_barrier();
  COMPUTE((NT - 1) & 3);

#undef STAGE
#undef COMPUTE

  // epilogue: C/D layout col = lane&15, row = (lane>>4)*4 + j  [m89/m91]
#pragma unroll
  for (int m = 0; m < MR; ++m)
#pragma unroll
    for (int n = 0; n < NR; ++n) {
      const int col = n0 + wc * 32 + n * 16 + l16;
      const float bv = bias[col];
#pragma unroll
      for (int j = 0; j < 4; ++j) {
        int row = m0 + wr * 64 + m * 16 + half * 4 + j;
        float v = fmaxf(acc[m][n][j] + bv, 0.0f);
        C[(long)row * N + col] = (__bf16)v;
      }
    }
}

// ---------------------------------------------------------------------------
// Fused dispatch: blocks [0,512) = qp GEMM; blocks [512,1024) = proto_partial.
// Both read emb and are independent -> overlap latency-bound proto under
// compute-bound qp, and save one dispatch.
//
// qp part: qp[8192][256] = q_emb @ WqT^T + b1 (f32), BM=64 BN=64 BK=32,
//   depth-3 quad-buffer, waits vmcnt(4)/2/0 (L=2). (R9-verified structure.)
// proto part: class partial sums, grid-slice (64 classes x 8 slices).
// ---------------------------------------------------------------------------
__global__ __launch_bounds__(256, 4) void qp_proto(
    const __bf16* __restrict__ emb, const __bf16* __restrict__ BT,
    const float* __restrict__ bias, float* __restrict__ Cqp,
    const int* __restrict__ labels, float* __restrict__ sums_part,
    int* __restrict__ cnt_part) {
  constexpr int BM = 64, BN = 64, BK = 32;
  constexpr int N = HIDDEN, K = D_EMB;
  constexpr int NT = K / BK;  // 16
  constexpr int MR = 2, NR = 2;

  __shared__ __align__(16) __bf16 As[4][BM * BK];  // 4 x 4 KB
  __shared__ __align__(16) __bf16 Bs[4][BN * BK];  // 4 x 4 KB

  const int tid = threadIdx.x;
  const int bid = blockIdx.x;

  if (bid >= 512) {
    // ---------------- proto_partial ----------------
    const int pb = bid - 512;
    const int c = pb >> 3;
    const int s = pb & 7;
    const int j0 = s * (N_SUPPORT / 8);
    float a0 = 0.0f, a1 = 0.0f;
    int count = 0;
#pragma unroll 4
    for (int j = j0; j < j0 + N_SUPPORT / 8; j += 4) {
      int4 lab4 = *(const int4*)(labels + j);
#pragma unroll
      for (int u = 0; u < 4; ++u) {
        int lab = (u == 0) ? lab4.x : (u == 1) ? lab4.y : (u == 2) ? lab4.z : lab4.w;
        if (lab == c) {
          const __bf16* r = emb + (long)(j + u) * D_EMB;
          a0 += (float)r[tid];
          a1 += (float)r[tid + 256];
          ++count;
        }
      }
    }
    float* dst = sums_part + (long)(c * 8 + s) * D_EMB;
    dst[tid] = a0;
    dst[tid + 256] = a1;
    if (tid == 0) cnt_part[c * 8 + s] = count;
    return;
  }

  // ---------------- qp GEMM ----------------
  const __bf16* A = emb + (long)N_SUPPORT * D_EMB;
  const int wave = tid >> 6, lane = tid & 63;
  const int wr = wave >> 1, wc = wave & 1;
  const int l16 = lane & 15, half = lane >> 4;
  const int slot = half ^ ((l16 >> 1) & 3);

  const int m0 = (bid & 127) * BM;
  const int n0 = (bid >> 7) * BN;

  const int srow = tid >> 2;
  const int skc = (tid & 3) ^ ((srow >> 1) & 3);
  const __bf16* aptr = A + (long)(m0 + srow) * K + skc * 8;
  const __bf16* bptr = BT + (long)(n0 + srow) * K + skc * 8;

  f32x4 acc[MR][NR];
#pragma unroll
  for (int m = 0; m < MR; ++m)
#pragma unroll
    for (int n = 0; n < NR; ++n) acc[m][n] = (f32x4)0.0f;

#define STAGE(t, buf)                                                       \
  {                                                                         \
    GLOAD_LDS16(aptr + (t) * BK, &As[buf][tid * 8]);                        \
    GLOAD_LDS16(bptr + (t) * BK, &Bs[buf][tid * 8]);                        \
  }

#define COMPUTE(buf)                                                        \
  {                                                                         \
    bf16x8 a[MR], b[NR];                                                    \
    _Pragma("unroll") for (int m = 0; m < MR; ++m)                          \
        a[m] = *(const bf16x8*)(&As[buf][(wr * 32 + m * 16 + l16) * BK +    \
                                         slot * 8]);                        \
    _Pragma("unroll") for (int n = 0; n < NR; ++n)                          \
        b[n] = *(const bf16x8*)(&Bs[buf][(wc * 32 + n * 16 + l16) * BK +    \
                                         slot * 8]);                        \
    asm volatile("s_waitcnt lgkmcnt(0)" ::: "memory");                      \
    __builtin_amdgcn_sched_barrier(0);                                      \
    _Pragma("unroll") for (int m = 0; m < MR; ++m)                          \
        _Pragma("unroll") for (int n = 0; n < NR; ++n)                      \
            acc[m][n] = __builtin_amdgcn_mfma_f32_16x16x32_bf16(            \
                a[m], b[n], acc[m][n], 0, 0, 0);                            \
  }

  STAGE(0, 0);
  STAGE(1, 1);
  STAGE(2, 2);
  asm volatile("s_waitcnt vmcnt(4)" ::: "memory");  // tile 0 landed
  __builtin_amdgcn_s_barrier();

  for (int t = 0; t < NT - 3; ++t) {
    STAGE(t + 3, (t + 3) & 3);
    COMPUTE(t & 3);
    asm volatile("s_waitcnt vmcnt(4)" ::: "memory");  // tile t+1 landed
    __builtin_amdgcn_s_barrier();
  }
  COMPUTE((NT - 3) & 3);
  asm volatile("s_waitcnt vmcnt(2)" ::: "memory");
  __builtin_amdgcn_s_barrier();
  COMPUTE((NT - 2) & 3);
  asm volatile("s_waitcnt vmcnt(0)" ::: "memory");
  __builtin_amdgcn_s_barrier();
  COMPUTE((NT - 1) & 3);

#undef STAGE
#undef COMPUTE

#pragma unroll
  for (int m = 0; m < MR; ++m)
#pragma unroll
    for (int n = 0; n < NR; ++n) {
      const int col = n0 + wc * 32 + n * 16 + l16;
      const float bv = bias[col];
#pragma unroll
      for (int j = 0; j < 4; ++j) {
        int row = m0 + wr * 32 + m * 16 + half * 4 + j;
        Cqp[(long)row * N + col] = acc[m][n][j] + bv;
      }
    }
}

// ---------------------------------------------------------------------------
// cpb_part[kc][c][n] = sum_{k in chunk kc} means[c][k] * W1[(D_EMB+k)][n]
// grid (64, 4). b1 folded into qp GEMM bias. Summed in score staging.
// ---------------------------------------------------------------------------
__global__ __launch_bounds__(256) void proto_cpb(
    const float* __restrict__ sums_part, const int* __restrict__ cnt_part,
    const float* __restrict__ W1, float* __restrict__ cpb_part) {
  __shared__ float ls[128];
  const int c = blockIdx.x;
  const int kc = blockIdx.y;
  const int k0 = kc * 128;
  const int tid = threadIdx.x;

  int nc = 0;
#pragma unroll
  for (int s = 0; s < 8; ++s) nc += cnt_part[c * 8 + s];
  float inv = 1.0f / fmaxf((float)nc, 1.0f);

  if (tid < 128) {
    float v = 0.0f;
#pragma unroll
    for (int s = 0; s < 8; ++s)
      v += sums_part[(long)(c * 8 + s) * D_EMB + k0 + tid];
    ls[tid] = v * inv;
  }
  __syncthreads();

  float acc = 0.0f;
#pragma unroll 8
  for (int k = 0; k < 128; ++k)
    acc = fmaf(ls[k], W1[(long)(D_EMB + k0 + k) * HIDDEN + tid], acc);
  cpb_part[((long)kc * NUM_CLASSES + c) * HIDDEN + tid] = acc;
}

// ---------------------------------------------------------------------------
// fused score: out[q][c] = sigmoid( sum_k relu(qp[q,k]+cpb[c,k]) * W2[k] + b2 )
// qp already includes b1. cpb_part summed during staging.
// lane = class c; wave handles 8 q-rows; block = 4 waves = 32 q-rows.
// ---------------------------------------------------------------------------
__global__ __launch_bounds__(256) void score_kernel(
    const float* __restrict__ qp, const float* __restrict__ cpb_part,
    const float* __restrict__ W2, const float* __restrict__ b2,
    float* __restrict__ out) {
  constexpr int CPB_S = 260;  // f32 stride: 1040 B, 16B aligned
  __shared__ __align__(16) float cpb_s[NUM_CLASSES * CPB_S];
  __shared__ __align__(16) float qp_s[32 * HIDDEN];
  __shared__ __align__(16) float w2_s[HIDDEN];

  const int tid = threadIdx.x;
  const int w = tid >> 6;
  const int c = tid & 63;
  const int qb0 = blockIdx.x * 32;
  constexpr int NCH = NUM_CLASSES * HIDDEN;

  w2_s[tid] = W2[tid];
  for (int i = tid; i < NCH; i += 256)
    cpb_s[(i >> 8) * CPB_S + (i & (HIDDEN - 1))] =
        cpb_part[i] + cpb_part[NCH + i] + cpb_part[2 * NCH + i] +
        cpb_part[3 * NCH + i];
  for (int i = tid; i < 32 * HIDDEN; i += 256)
    qp_s[i] = qp[(long)qb0 * HIDDEN + i];
  __syncthreads();

  const float bb = b2[0];
  float acc[8];
#pragma unroll
  for (int q = 0; q < 8; ++q) acc[q] = 0.0f;

  const float* crow = cpb_s + c * CPB_S;
  const float* qbase = qp_s + (w * 8) * HIDDEN;

#pragma unroll 4
  for (int kc = 0; kc < HIDDEN / 4; ++kc) {
    f32x4 cv = *(const f32x4*)(crow + kc * 4);
    f32x4 wv = *(const f32x4*)(w2_s + kc * 4);
#pragma unroll
    for (int q = 0; q < 8; ++q) {
      f32x4 qv = *(const f32x4*)(qbase + q * HIDDEN + kc * 4);
      acc[q] = fmaf(fmaxf(qv[0] + cv[0], 0.0f), wv[0], acc[q]);
      acc[q] = fmaf(fmaxf(qv[1] + cv[1], 0.0f), wv[1], acc[q]);
      acc[q] = fmaf(fmaxf(qv[2] + cv[2], 0.0f), wv[2], acc[q]);
      acc[q] = fmaf(fmaxf(qv[3] + cv[3], 0.0f), wv[3], acc[q]);
    }
  }

#pragma unroll
  for (int q = 0; q < 8; ++q) {
    float x = acc[q] + bb;
    out[(long)(qb0 + w * 8 + q) * NUM_CLASSES + c] = 1.0f / (1.0f + __expf(-x));
  }
}

// ---------------------------------------------------------------------------
extern "C" void kernel_launch(void* const* d_in, const int* in_sizes, int n_in,
                              void* d_out, int out_size, void* d_ws,
                              size_t ws_size, hipStream_t stream) {
  const float* support = (const float*)d_in[0];
  const float* query   = (const float*)d_in[1];
  const int*   labels  = (const int*)d_in[2];
  const float* W_e     = (const float*)d_in[3];
  const float* b_e     = (const float*)d_in[4];
  const float* W1      = (const float*)d_in[5];
  const float* b1      = (const float*)d_in[6];
  const float* W2      = (const float*)d_in[7];
  const float* b2      = (const float*)d_in[8];
  float* out = (float*)d_out;

  char* ws = (char*)d_ws;
  size_t off = 0;
  auto alloc = [&](size_t bytes) {
    void* p = ws + off;
    off = (off + bytes + 255) & ~(size_t)255;
    return p;
  };
  const long NTOT = N_SUPPORT + N_QUERY;  // 12288
  __bf16* Xbf = (__bf16*)alloc((size_t)NTOT * D_IN * 2);            // 25.2 MB
  __bf16* WeT = (__bf16*)alloc((size_t)D_EMB * D_IN * 2);           // 1 MB
  __bf16* WqT = (__bf16*)alloc((size_t)HIDDEN * D_EMB * 2);         // 256 KB
  __bf16* emb = (__bf16*)alloc((size_t)NTOT * D_EMB * 2);           // 12.6 MB
  float*  qp  = (float*)alloc((size_t)N_QUERY * HIDDEN * 4);        // 8.4 MB
  float*  sums_part = (float*)alloc((size_t)NUM_CLASSES * 8 * D_EMB * 4);
  int*    cnt_part  = (int*)alloc((size_t)NUM_CLASSES * 8 * 4);
  float*  cpb_part  = (float*)alloc((size_t)4 * NUM_CLASSES * HIDDEN * 4);

  // transposes + fp32->bf16 convert, one dispatch
  prep<<<640 + (int)(NTOT * D_IN / 4096), 256, 0, stream>>>(
      W_e, W1, support, query, WeT, WqT, Xbf);

  // embeddings: relu(Xbf @ W_e + b_e) -> bf16 [12288][512], depth-3 pipeline
  gemm_emb<<<dim3(NTOT / 128, D_EMB / 64), 256, 0, stream>>>(
      Xbf, WeT, b_e, emb);

  // fused: qp GEMM (blocks 0..511) + class partial sums (blocks 512..1023)
  qp_proto<<<1024, 256, 0, stream>>>(emb, WqT, b1, qp, labels, sums_part,
                                     cnt_part);

  // prototype projection parts
  proto_cpb<<<dim3(NUM_CLASSES, 4), 256, 0, stream>>>(sums_part, cnt_part, W1,
                                                      cpb_part);

  // fused relation score (cpb_part summed in staging)
  score_kernel<<<N_QUERY / 32, 256, 0, stream>>>(qp, cpb_part, W2, b2, out);
}

// Round 11
// 81.205 us; speedup vs baseline: 1.4325x; 1.0781x over previous
//
#include <hip/hip_runtime.h>
#include <hip/hip_bf16.h>

// Problem constants
#define D_IN 1024
#define D_EMB 512
#define HIDDEN 256
#define NUM_CLASSES 64
#define N_SUPPORT 4096
#define N_QUERY 8192

typedef __bf16 bf16x8 __attribute__((ext_vector_type(8)));
typedef __bf16 bf16x4 __attribute__((ext_vector_type(4)));
typedef float f32x4 __attribute__((ext_vector_type(4)));

#define GLOAD_LDS16(g, l)                                                          \
  __builtin_amdgcn_global_load_lds(                                                \
      (const __attribute__((address_space(1))) unsigned int*)(g),                  \
      (__attribute__((address_space(3))) unsigned int*)(l), 16, 0, 0)

// ---------------------------------------------------------------------------
// prep: weight transposes + fp32->bf16 convert (one dispatch)
//   blocks [0,512):    W_e [1024][512] -> WeT [512][1024]
//   blocks [512,640):  W1[:512][256]   -> WqT [256][512]
//   blocks [640,3712): [support;query] fp32 -> Xbf bf16, 4096 elems/block
// ---------------------------------------------------------------------------
__global__ __launch_bounds__(256) void prep(
    const float* __restrict__ W_e, const float* __restrict__ W1,
    const float* __restrict__ support, const float* __restrict__ query,
    __bf16* __restrict__ WeT, __bf16* __restrict__ WqT,
    __bf16* __restrict__ Xbf) {
  const int tid = threadIdx.x;
  int b = blockIdx.x;
  if (b < 640) {
    __shared__ float tile[32][33];
    const float* in;
    __bf16* out;
    int bx, by, rows, cols;
    if (b < 512) {
      in = W_e; out = WeT; rows = D_IN; cols = D_EMB;
      bx = (b & 15) * 32; by = (b >> 4) * 32;
    } else {
      b -= 512;
      in = W1; out = WqT; rows = D_EMB; cols = HIDDEN;  // W1[:512] only
      bx = (b & 7) * 32; by = (b >> 3) * 32;
    }
    int tx = tid & 31, ty = tid >> 5;
#pragma unroll
    for (int i = ty; i < 32; i += 8)
      tile[i][tx] = in[(long)(by + i) * cols + bx + tx];
    __syncthreads();
#pragma unroll
    for (int i = ty; i < 32; i += 8)
      out[(long)(bx + i) * rows + by + tx] = (__bf16)tile[tx][i];
  } else {
    const long nsup = (long)N_SUPPORT * D_IN;
    long base = (long)(b - 640) * 4096;
#pragma unroll
    for (int g = 0; g < 4; ++g) {
      long i = base + g * 1024 + tid * 4;
      const float* src = (i < nsup) ? (support + i) : (query + (i - nsup));
      float4 v = *(const float4*)src;
      bf16x4 o;
      o[0] = (__bf16)v.x; o[1] = (__bf16)v.y;
      o[2] = (__bf16)v.z; o[3] = (__bf16)v.w;
      *(bf16x4*)(Xbf + i) = o;
    }
  }
}

// ---------------------------------------------------------------------------
// Embedding GEMM, bf16 A, BK=64 (16 MFMA/wave/step, 16 steps), 2 LDS buffers:
//   emb[12288][512] = relu( Xbf @ WeT^T + b_e ) -> bf16
// BM=128, BN=64. LDS 48 KB -> 3 blocks/CU. Stage(t+1) issued BEFORE
// compute(t) -> 6 loads/thread get the whole compute phase as cover;
// vmcnt(0)+s_barrier once per step (half as many syncs as BK=32).
// Swizzle (rule #21): rows are 8x16B slots; dest linear, source column
// ^= (row&7), read slot ^= (row&7). row&7 == l16&7 at read time.
// grid (96,8): same m-tile's n-tiles land on one XCD (96%8==0) -> A L2-hot.
// ---------------------------------------------------------------------------
__global__ __launch_bounds__(256, 3) void gemm_emb(
    const __bf16* __restrict__ A, const __bf16* __restrict__ BT,
    const float* __restrict__ bias, __bf16* __restrict__ C) {
  constexpr int BM = 128, BN = 64, BK = 64;
  constexpr int N = D_EMB, K = D_IN;
  constexpr int NT = K / BK;  // 16
  constexpr int MR = 4, NR = 2;

  __shared__ __align__(16) __bf16 As[2][BM * BK];  // 2 x 16 KB
  __shared__ __align__(16) __bf16 Bs[2][BN * BK];  // 2 x 8 KB

  const int tid = threadIdx.x;
  const int wave = tid >> 6, lane = tid & 63;
  const int wr = wave >> 1, wc = wave & 1;
  const int l16 = lane & 15, half = lane >> 4;
  const int r7 = l16 & 7;  // read-swizzle key (row & 7)

  const int m0 = blockIdx.x * BM;
  const int n0 = blockIdx.y * BN;

  // staging: chunk = 16B piece; 8 chunks per 128B row; source column
  // pre-swizzled by row&7, dest linear (both-sides rule).
  // A: 1024 chunks -> 4/thread; B: 512 chunks -> 2/thread.
  const __bf16* aptr[4];
#pragma unroll
  for (int q = 0; q < 4; ++q) {
    int chunk = q * 256 + tid;
    int row = chunk >> 3;
    int kc = (chunk & 7) ^ (row & 7);
    aptr[q] = A + (long)(m0 + row) * K + kc * 8;
  }
  const __bf16* bptr[2];
#pragma unroll
  for (int q = 0; q < 2; ++q) {
    int chunk = q * 256 + tid;
    int row = chunk >> 3;
    int kc = (chunk & 7) ^ (row & 7);
    bptr[q] = BT + (long)(n0 + row) * K + kc * 8;
  }

  f32x4 acc[MR][NR];
#pragma unroll
  for (int m = 0; m < MR; ++m)
#pragma unroll
    for (int n = 0; n < NR; ++n) acc[m][n] = (f32x4)0.0f;

#define STAGE(t, buf)                                                       \
  {                                                                         \
    _Pragma("unroll") for (int q = 0; q < 4; ++q)                           \
        GLOAD_LDS16(aptr[q] + (t) * BK, &As[buf][(q * 256 + tid) * 8]);     \
    _Pragma("unroll") for (int q = 0; q < 2; ++q)                           \
        GLOAD_LDS16(bptr[q] + (t) * BK, &Bs[buf][(q * 256 + tid) * 8]);     \
  }

#define COMPUTE(buf)                                                        \
  {                                                                         \
    bf16x8 a[MR][2], b[NR][2];                                              \
    _Pragma("unroll") for (int m = 0; m < MR; ++m) {                        \
      int row = wr * 64 + m * 16 + l16;                                     \
      _Pragma("unroll") for (int ks = 0; ks < 2; ++ks)                      \
          a[m][ks] = *(const bf16x8*)(&As[buf][row * BK +                   \
                                      (((ks * 4 + half) ^ r7) * 8)]);       \
    }                                                                       \
    _Pragma("unroll") for (int n = 0; n < NR; ++n) {                        \
      int row = wc * 32 + n * 16 + l16;                                     \
      _Pragma("unroll") for (int ks = 0; ks < 2; ++ks)                      \
          b[n][ks] = *(const bf16x8*)(&Bs[buf][row * BK +                   \
                                      (((ks * 4 + half) ^ r7) * 8)]);       \
    }                                                                       \
    asm volatile("s_waitcnt lgkmcnt(0)" ::: "memory");                      \
    __builtin_amdgcn_sched_barrier(0);                                      \
    _Pragma("unroll") for (int ks = 0; ks < 2; ++ks)                        \
        _Pragma("unroll") for (int m = 0; m < MR; ++m)                      \
            _Pragma("unroll") for (int n = 0; n < NR; ++n)                  \
                acc[m][n] = __builtin_amdgcn_mfma_f32_16x16x32_bf16(        \
                    a[m][ks], b[n][ks], acc[m][n], 0, 0, 0);                \
  }

  // prologue: stage tile 0
  STAGE(0, 0);
  asm volatile("s_waitcnt vmcnt(0)" ::: "memory");
  __builtin_amdgcn_s_barrier();

  int cur = 0;
  for (int t = 0; t < NT - 1; ++t) {
    STAGE(t + 1, cur ^ 1);  // issue BEFORE compute: full-phase latency cover
    COMPUTE(cur);
    asm volatile("s_waitcnt vmcnt(0)" ::: "memory");  // t+1 landed
    __builtin_amdgcn_s_barrier();
    cur ^= 1;
  }
  COMPUTE(cur);

#undef STAGE
#undef COMPUTE

  // epilogue: C/D layout col = lane&15, row = (lane>>4)*4 + j  [m89/m91]
#pragma unroll
  for (int m = 0; m < MR; ++m)
#pragma unroll
    for (int n = 0; n < NR; ++n) {
      const int col = n0 + wc * 32 + n * 16 + l16;
      const float bv = bias[col];
#pragma unroll
      for (int j = 0; j < 4; ++j) {
        int row = m0 + wr * 64 + m * 16 + half * 4 + j;
        float v = fmaxf(acc[m][n][j] + bv, 0.0f);
        C[(long)row * N + col] = (__bf16)v;
      }
    }
}

// ---------------------------------------------------------------------------
// Fused dispatch: blocks [0,512) = qp GEMM; blocks [512,1024) = proto_partial.
// (R10-verified structure, unchanged.)
// ---------------------------------------------------------------------------
__global__ __launch_bounds__(256, 4) void qp_proto(
    const __bf16* __restrict__ emb, const __bf16* __restrict__ BT,
    const float* __restrict__ bias, float* __restrict__ Cqp,
    const int* __restrict__ labels, float* __restrict__ sums_part,
    int* __restrict__ cnt_part) {
  constexpr int BM = 64, BN = 64, BK = 32;
  constexpr int N = HIDDEN, K = D_EMB;
  constexpr int NT = K / BK;  // 16
  constexpr int MR = 2, NR = 2;

  __shared__ __align__(16) __bf16 As[4][BM * BK];  // 4 x 4 KB
  __shared__ __align__(16) __bf16 Bs[4][BN * BK];  // 4 x 4 KB

  const int tid = threadIdx.x;
  const int bid = blockIdx.x;

  if (bid >= 512) {
    // ---------------- proto_partial ----------------
    const int pb = bid - 512;
    const int c = pb >> 3;
    const int s = pb & 7;
    const int j0 = s * (N_SUPPORT / 8);
    float a0 = 0.0f, a1 = 0.0f;
    int count = 0;
#pragma unroll 4
    for (int j = j0; j < j0 + N_SUPPORT / 8; j += 4) {
      int4 lab4 = *(const int4*)(labels + j);
#pragma unroll
      for (int u = 0; u < 4; ++u) {
        int lab = (u == 0) ? lab4.x : (u == 1) ? lab4.y : (u == 2) ? lab4.z : lab4.w;
        if (lab == c) {
          const __bf16* r = emb + (long)(j + u) * D_EMB;
          a0 += (float)r[tid];
          a1 += (float)r[tid + 256];
          ++count;
        }
      }
    }
    float* dst = sums_part + (long)(c * 8 + s) * D_EMB;
    dst[tid] = a0;
    dst[tid + 256] = a1;
    if (tid == 0) cnt_part[c * 8 + s] = count;
    return;
  }

  // ---------------- qp GEMM ----------------
  const __bf16* A = emb + (long)N_SUPPORT * D_EMB;
  const int wave = tid >> 6, lane = tid & 63;
  const int wr = wave >> 1, wc = wave & 1;
  const int l16 = lane & 15, half = lane >> 4;
  const int slot = half ^ ((l16 >> 1) & 3);

  const int m0 = (bid & 127) * BM;
  const int n0 = (bid >> 7) * BN;

  const int srow = tid >> 2;
  const int skc = (tid & 3) ^ ((srow >> 1) & 3);
  const __bf16* aptr = A + (long)(m0 + srow) * K + skc * 8;
  const __bf16* bptr = BT + (long)(n0 + srow) * K + skc * 8;

  f32x4 acc[MR][NR];
#pragma unroll
  for (int m = 0; m < MR; ++m)
#pragma unroll
    for (int n = 0; n < NR; ++n) acc[m][n] = (f32x4)0.0f;

#define STAGE(t, buf)                                                       \
  {                                                                         \
    GLOAD_LDS16(aptr + (t) * BK, &As[buf][tid * 8]);                        \
    GLOAD_LDS16(bptr + (t) * BK, &Bs[buf][tid * 8]);                        \
  }

#define COMPUTE(buf)                                                        \
  {                                                                         \
    bf16x8 a[MR], b[NR];                                                    \
    _Pragma("unroll") for (int m = 0; m < MR; ++m)                          \
        a[m] = *(const bf16x8*)(&As[buf][(wr * 32 + m * 16 + l16) * BK +    \
                                         slot * 8]);                        \
    _Pragma("unroll") for (int n = 0; n < NR; ++n)                          \
        b[n] = *(const bf16x8*)(&Bs[buf][(wc * 32 + n * 16 + l16) * BK +    \
                                         slot * 8]);                        \
    asm volatile("s_waitcnt lgkmcnt(0)" ::: "memory");                      \
    __builtin_amdgcn_sched_barrier(0);                                      \
    _Pragma("unroll") for (int m = 0; m < MR; ++m)                          \
        _Pragma("unroll") for (int n = 0; n < NR; ++n)                      \
            acc[m][n] = __builtin_amdgcn_mfma_f32_16x16x32_bf16(            \
                a[m], b[n], acc[m][n], 0, 0, 0);                            \
  }

  STAGE(0, 0);
  STAGE(1, 1);
  STAGE(2, 2);
  asm volatile("s_waitcnt vmcnt(4)" ::: "memory");  // tile 0 landed
  __builtin_amdgcn_s_barrier();

  for (int t = 0; t < NT - 3; ++t) {
    STAGE(t + 3, (t + 3) & 3);
    COMPUTE(t & 3);
    asm volatile("s_waitcnt vmcnt(4)" ::: "memory");  // tile t+1 landed
    __builtin_amdgcn_s_barrier();
  }
  COMPUTE((NT - 3) & 3);
  asm volatile("s_waitcnt vmcnt(2)" ::: "memory");
  __builtin_amdgcn_s_barrier();
  COMPUTE((NT - 2) & 3);
  asm volatile("s_waitcnt vmcnt(0)" ::: "memory");
  __builtin_amdgcn_s_barrier();
  COMPUTE((NT - 1) & 3);

#undef STAGE
#undef COMPUTE

#pragma unroll
  for (int m = 0; m < MR; ++m)
#pragma unroll
    for (int n = 0; n < NR; ++n) {
      const int col = n0 + wc * 32 + n * 16 + l16;
      const float bv = bias[col];
#pragma unroll
      for (int j = 0; j < 4; ++j) {
        int row = m0 + wr * 32 + m * 16 + half * 4 + j;
        Cqp[(long)row * N + col] = acc[m][n][j] + bv;
      }
    }
}

// ---------------------------------------------------------------------------
// cpb_part[kc][c][n] = sum_{k in chunk kc} means[c][k] * W1[(D_EMB+k)][n]
// grid (64, 4). b1 folded into qp GEMM bias. Summed in score staging.
// ---------------------------------------------------------------------------
__global__ __launch_bounds__(256) void proto_cpb(
    const float* __restrict__ sums_part, const int* __restrict__ cnt_part,
    const float* __restrict__ W1, float* __restrict__ cpb_part) {
  __shared__ float ls[128];
  const int c = blockIdx.x;
  const int kc = blockIdx.y;
  const int k0 = kc * 128;
  const int tid = threadIdx.x;

  int nc = 0;
#pragma unroll
  for (int s = 0; s < 8; ++s) nc += cnt_part[c * 8 + s];
  float inv = 1.0f / fmaxf((float)nc, 1.0f);

  if (tid < 128) {
    float v = 0.0f;
#pragma unroll
    for (int s = 0; s < 8; ++s)
      v += sums_part[(long)(c * 8 + s) * D_EMB + k0 + tid];
    ls[tid] = v * inv;
  }
  __syncthreads();

  float acc = 0.0f;
#pragma unroll 8
  for (int k = 0; k < 128; ++k)
    acc = fmaf(ls[k], W1[(long)(D_EMB + k0 + k) * HIDDEN + tid], acc);
  cpb_part[((long)kc * NUM_CLASSES + c) * HIDDEN + tid] = acc;
}

// ---------------------------------------------------------------------------
// fused score: out[q][c] = sigmoid( sum_k relu(qp[q,k]+cpb[c,k]) * W2[k] + b2 )
// qp already includes b1. cpb_part summed during staging.
// lane = class c; wave handles 8 q-rows; block = 4 waves = 32 q-rows.
// ---------------------------------------------------------------------------
__global__ __launch_bounds__(256) void score_kernel(
    const float* __restrict__ qp, const float* __restrict__ cpb_part,
    const float* __restrict__ W2, const float* __restrict__ b2,
    float* __restrict__ out) {
  constexpr int CPB_S = 260;  // f32 stride: 1040 B, 16B aligned
  __shared__ __align__(16) float cpb_s[NUM_CLASSES * CPB_S];
  __shared__ __align__(16) float qp_s[32 * HIDDEN];
  __shared__ __align__(16) float w2_s[HIDDEN];

  const int tid = threadIdx.x;
  const int w = tid >> 6;
  const int c = tid & 63;
  const int qb0 = blockIdx.x * 32;
  constexpr int NCH = NUM_CLASSES * HIDDEN;

  w2_s[tid] = W2[tid];
  for (int i = tid; i < NCH; i += 256)
    cpb_s[(i >> 8) * CPB_S + (i & (HIDDEN - 1))] =
        cpb_part[i] + cpb_part[NCH + i] + cpb_part[2 * NCH + i] +
        cpb_part[3 * NCH + i];
  for (int i = tid; i < 32 * HIDDEN; i += 256)
    qp_s[i] = qp[(long)qb0 * HIDDEN + i];
  __syncthreads();

  const float bb = b2[0];
  float acc[8];
#pragma unroll
  for (int q = 0; q < 8; ++q) acc[q] = 0.0f;

  const float* crow = cpb_s + c * CPB_S;
  const float* qbase = qp_s + (w * 8) * HIDDEN;

#pragma unroll 4
  for (int kc = 0; kc < HIDDEN / 4; ++kc) {
    f32x4 cv = *(const f32x4*)(crow + kc * 4);
    f32x4 wv = *(const f32x4*)(w2_s + kc * 4);
#pragma unroll
    for (int q = 0; q < 8; ++q) {
      f32x4 qv = *(const f32x4*)(qbase + q * HIDDEN + kc * 4);
      acc[q] = fmaf(fmaxf(qv[0] + cv[0], 0.0f), wv[0], acc[q]);
      acc[q] = fmaf(fmaxf(qv[1] + cv[1], 0.0f), wv[1], acc[q]);
      acc[q] = fmaf(fmaxf(qv[2] + cv[2], 0.0f), wv[2], acc[q]);
      acc[q] = fmaf(fmaxf(qv[3] + cv[3], 0.0f), wv[3], acc[q]);
    }
  }

#pragma unroll
  for (int q = 0; q < 8; ++q) {
    float x = acc[q] + bb;
    out[(long)(qb0 + w * 8 + q) * NUM_CLASSES + c] = 1.0f / (1.0f + __expf(-x));
  }
}

// ---------------------------------------------------------------------------
extern "C" void kernel_launch(void* const* d_in, const int* in_sizes, int n_in,
                              void* d_out, int out_size, void* d_ws,
                              size_t ws_size, hipStream_t stream) {
  const float* support = (const float*)d_in[0];
  const float* query   = (const float*)d_in[1];
  const int*   labels  = (const int*)d_in[2];
  const float* W_e     = (const float*)d_in[3];
  const float* b_e     = (const float*)d_in[4];
  const float* W1      = (const float*)d_in[5];
  const float* b1      = (const float*)d_in[6];
  const float* W2      = (const float*)d_in[7];
  const float* b2      = (const float*)d_in[8];
  float* out = (float*)d_out;

  char* ws = (char*)d_ws;
  size_t off = 0;
  auto alloc = [&](size_t bytes) {
    void* p = ws + off;
    off = (off + bytes + 255) & ~(size_t)255;
    return p;
  };
  const long NTOT = N_SUPPORT + N_QUERY;  // 12288
  __bf16* Xbf = (__bf16*)alloc((size_t)NTOT * D_IN * 2);            // 25.2 MB
  __bf16* WeT = (__bf16*)alloc((size_t)D_EMB * D_IN * 2);           // 1 MB
  __bf16* WqT = (__bf16*)alloc((size_t)HIDDEN * D_EMB * 2);         // 256 KB
  __bf16* emb = (__bf16*)alloc((size_t)NTOT * D_EMB * 2);           // 12.6 MB
  float*  qp  = (float*)alloc((size_t)N_QUERY * HIDDEN * 4);        // 8.4 MB
  float*  sums_part = (float*)alloc((size_t)NUM_CLASSES * 8 * D_EMB * 4);
  int*    cnt_part  = (int*)alloc((size_t)NUM_CLASSES * 8 * 4);
  float*  cpb_part  = (float*)alloc((size_t)4 * NUM_CLASSES * HIDDEN * 4);

  // transposes + fp32->bf16 convert, one dispatch
  prep<<<640 + (int)(NTOT * D_IN / 4096), 256, 0, stream>>>(
      W_e, W1, support, query, WeT, WqT, Xbf);

  // embeddings: relu(Xbf @ W_e + b_e) -> bf16 [12288][512], BK=64 pipeline
  gemm_emb<<<dim3(NTOT / 128, D_EMB / 64), 256, 0, stream>>>(
      Xbf, WeT, b_e, emb);

  // fused: qp GEMM (blocks 0..511) + class partial sums (blocks 512..1023)
  qp_proto<<<1024, 256, 0, stream>>>(emb, WqT, b1, qp, labels, sums_part,
                                     cnt_part);

  // prototype projection parts
  proto_cpb<<<dim3(NUM_CLASSES, 4), 256, 0, stream>>>(sums_part, cnt_part, W1,
                                                      cpb_part);

  // fused relation score (cpb_part summed in staging)
  score_kernel<<<N_QUERY / 32, 256, 0, stream>>>(qp, cpb_part, W2, b2, out);
}